// Round 13
// baseline (551.185 us; speedup 1.0000x reference)
//
#include <hip/hip_runtime.h>
#include <hip/hip_bf16.h>
#include <math.h>

// Problem constants: B(=T)=8, C=256, H=W=64, N=4096, heads=8, d=32.
#define T_ 8
#define C_ 256
#define N_ 4096          // H*W
#define CN_ (C_ * N_)    // 1048576 elements per timestep
#define EPSB 1e-5f

typedef unsigned long long u64;
typedef unsigned int u32;
typedef short bf16x8 __attribute__((ext_vector_type(8)));
typedef float f32x4 __attribute__((ext_vector_type(4)));

static __device__ __forceinline__ unsigned short f2bf(float f) {
    __hip_bfloat16 h = __float2bfloat16(f);   // RTNE
    return *(unsigned short*)&h;
}
static __device__ __forceinline__ float bf2f(unsigned short u) {
    u32 x = (u32)u << 16;                     // exact widen
    return *(float*)&x;
}

// Fragment tiling: a 16(row) x 32(k) tile stored as [lane 64][8 shorts],
// lane = ((k>>3)&3)*16 + (row&15), j = k&7. Tile stride 512 shorts.
// pos(n,k) = ((n>>4)*8 + (k>>5))*512 + (((k>>3)&3)*16 + (n&15))*8 + (k&7).

// ---------------------------------------------------------------------------
// FUSED: LIF(x) + fragment layout. Block = 8-channel octet x 32 n.
__global__ __launch_bounds__(256) void lif_x_frag(const float* __restrict__ X,
                                                  unsigned short* __restrict__ ST) {
    int nb = blockIdx.x * 32;
    int c0 = blockIdx.y * 8;
    int tid = threadIdx.x;
    int nj = tid & 31, ci = tid >> 5;
    size_t base = (size_t)(c0 + ci) * N_ + nb + nj;
    __shared__ unsigned short Ls[8][34];
    int k32 = c0 >> 5, quad = (c0 >> 3) & 3;
    float v = 0.f;
#pragma unroll
    for (int t = 0; t < T_; t++) {
        float xt = X[(size_t)t * CN_ + base];
        v = v + (xt - v) / 2.0f;
        int s = (v - 1.0f >= 0.f) ? 1 : 0;
        Ls[ci][nj] = s ? (unsigned short)0x3F80 : (unsigned short)0;
        if (s) v = 0.f;
        __syncthreads();
        if (tid < 32) {
            int np = nb + tid;
            bf16x8 bs;
#pragma unroll
            for (int j = 0; j < 8; j++) bs[j] = (short)Ls[j][tid];
            *(bf16x8*)&ST[(size_t)t * CN_ +
                ((size_t)((np >> 4) * 8 + k32)) * 512 + (quad * 16 + (np & 15)) * 8] = bs;
        }
        __syncthreads();
    }
}

// ---------------------------------------------------------------------------
// Branch-indexed LIF: br 0 -> u8 spikes (q), br 1/2 -> bitpacked (k, v).
struct LArgs {
    const float* F[3];
    unsigned char* sq;
    u64* kbp;
    u64* vbp;
};
__global__ __launch_bounds__(256) void lif3(LArgs a) {
    int br = blockIdx.y;
    int idx = blockIdx.x * 256 + threadIdx.x;
    const float* X = a.F[br];
    int lane = threadIdx.x & 63;
    u64* BP = (br == 1) ? a.kbp : a.vbp;
    float v = 0.f;
#pragma unroll
    for (int t = 0; t < T_; t++) {
        float xt = X[(size_t)t * CN_ + idx];
        v = v + (xt - v) / 2.0f;
        int s = (v - 1.0f >= 0.f) ? 1 : 0;
        if (br == 0) {
            a.sq[(size_t)t * CN_ + idx] = (unsigned char)s;
        } else {
            u64 mask = __ballot(s);
            if (lane == 0) BP[((size_t)t * CN_ + idx) >> 6] = mask;
        }
        if (s) v = 0.f;
    }
}

// ---------------------------------------------------------------------------
// Exact 3-way bf16 split of the eight 256x256 weights -> A-fragment layout.
struct WPtrs { const float* w[8]; };
__global__ __launch_bounds__(256) void split_w(WPtrs p, unsigned short* __restrict__ out) {
    int mat = blockIdx.y;
    int idx = blockIdx.x * 256 + threadIdx.x;   // = m*256 + k
    int m = idx >> 8, k = idx & 255;
    float w = p.w[mat][idx];
    unsigned short h1 = f2bf(w);
    float f1 = bf2f(h1);
    unsigned short h2 = f2bf(w - f1);
    unsigned short h3 = f2bf(w - f1 - bf2f(h2));   // exact: 8+8+8 bits
    int lane = ((k >> 3) & 3) * 16 + (m & 15);
    size_t pos = ((size_t)(((m >> 4) * 8 + (k >> 5)) * 64 + lane)) * 8 + (k & 7);
    size_t base = (size_t)mat * 3 * 65536;
    out[base + pos] = h1;
    out[base + 65536 + pos] = h2;
    out[base + 2 * 65536 + pos] = h3;
}

// ---------------------------------------------------------------------------
// Core of the fused dw+BN+pad+split (R9-verified arithmetic), parameterized.
static __device__ __forceinline__ void dw_body(const float* __restrict__ Yt,
                                               const float* __restrict__ dw,
                                               const float* __restrict__ bnp,
                                               unsigned short* __restrict__ Bh,
                                               unsigned short* __restrict__ Bl,
                                               int y0, int cg, int tid) {
    int c0 = cg * 8;
    __shared__ float L[8][6][68];
    __shared__ float invs[8], bs_[8], ms_[8], pads_[8];

    if (tid < 8) {
        int c = c0 + tid;
        float w = bnp[c], b = bnp[256 + c], m = bnp[512 + c], var = bnp[768 + c];
        float sq = sqrtf(var + EPSB);
        invs[tid] = w / sq;
        bs_[tid] = b;
        ms_[tid] = m;
        pads_[tid] = b - (m * w) / sq;
    }
    __syncthreads();

    for (int i = tid; i < 8 * 6 * 66; i += 256) {
        int c = i / 396;
        int rem = i - c * 396;
        int row = rem / 66, col = rem - row * 66;
        int gy = y0 - 1 + row, gx = col - 1;
        float val;
        if (gy < 0 || gy > 63 || gx < 0 || gx > 63) val = pads_[c];
        else val = (Yt[(size_t)(c0 + c) * N_ + gy * 64 + gx] - ms_[c]) * invs[c] + bs_[c];
        L[c][row][col] = val;
    }
    __syncthreads();

    int x = tid & 63, ry = tid >> 6;
    int n = (y0 + ry) * 64 + x;

    bf16x8 hi, lo;
#pragma unroll
    for (int j = 0; j < 8; j++) {
        const float* dwc = dw + (c0 + j) * 9;
        float a = 0.f;
#pragma unroll
        for (int dy = 0; dy < 3; dy++)
#pragma unroll
            for (int dx = 0; dx < 3; dx++)
                a += dwc[dy * 3 + dx] * L[j][ry + dy][x + dx];
        unsigned short h = f2bf(a);
        hi[j] = (short)h;
        lo[j] = (short)f2bf(a - bf2f(h));
    }
    size_t pos = ((size_t)((n >> 4) * 8 + (cg >> 2))) * 512 +
                 (size_t)(((cg & 3) * 16 + (n & 15)) * 8);
    *(bf16x8*)&Bh[pos] = hi;
    *(bf16x8*)&Bl[pos] = lo;
}

// Single-branch version (p chain).
__global__ __launch_bounds__(256) void dw_bn_split(const float* __restrict__ Yin,
                                                   const float* __restrict__ dw,
                                                   const float* __restrict__ bnp,
                                                   unsigned short* __restrict__ BhT,
                                                   unsigned short* __restrict__ BlT) {
    int t = blockIdx.z;
    dw_body(Yin + (size_t)t * CN_, dw, bnp,
            BhT + (size_t)t * CN_, BlT + (size_t)t * CN_,
            blockIdx.x * 4, blockIdx.y, threadIdx.x);
}

// Three-branch version (q,k,v in one dispatch). z: br = z>>3, t = z&7.
struct DArgs {
    const float* F[3];
    const float* dw[3];
    const float* bn[3];
    unsigned short* Ph[3];
    unsigned short* Pl[3];
};
__global__ __launch_bounds__(256) void dw3(DArgs a) {
    int br = blockIdx.z >> 3, t = blockIdx.z & 7;
    dw_body(a.F[br] + (size_t)t * CN_, a.dw[br], a.bn[br],
            a.Ph[br] + (size_t)t * CN_, a.Pl[br] + (size_t)t * CN_,
            blockIdx.x * 4, blockIdx.y, threadIdx.x);
}

// ---------------------------------------------------------------------------
// MFMA GEMM cores, reduced accumulator footprint for 3 waves/SIMD occupancy:
// block tile 128m x 64n, 4 waves (2x2), wave = 64m x 32n -> acc 4x2 f32x4
// (32 acc regs/thread vs 64 before). Same k32/split order per output element
// as R9 -> bit-identical results.
static __device__ __forceinline__ void gemm_s_core(const unsigned short* __restrict__ Wsp,
                                                   const unsigned short* __restrict__ Bt,
                                                   float* __restrict__ Yt,
                                                   int bx, int by, int tid) {
    int l = tid & 63, wave = tid >> 6;
    int wm = wave >> 1, wn = wave & 1;
    int lcol = l & 15, quad = l >> 4;

    f32x4 acc[4][2];
#pragma unroll
    for (int i = 0; i < 4; i++)
#pragma unroll
        for (int j = 0; j < 2; j++) acc[i][j] = (f32x4){0.f, 0.f, 0.f, 0.f};

#pragma unroll 2
    for (int k32 = 0; k32 < 8; k32++) {
        bf16x8 bfr[2];
#pragma unroll
        for (int nt = 0; nt < 2; nt++)
            bfr[nt] = *(const bf16x8*)&Bt[((size_t)((bx * 4 + wn * 2 + nt) * 8 + k32)) * 512 + l * 8];
#pragma unroll
        for (int s = 0; s < 3; s++) {
            const unsigned short* Ws = Wsp + (size_t)s * 65536;
#pragma unroll
            for (int mt = 0; mt < 4; mt++) {
                bf16x8 afr = *(const bf16x8*)&Ws[((size_t)((by * 8 + wm * 4 + mt) * 8 + k32)) * 512 + l * 8];
#pragma unroll
                for (int nt = 0; nt < 2; nt++)
                    acc[mt][nt] = __builtin_amdgcn_mfma_f32_16x16x32_bf16(
                        afr, bfr[nt], acc[mt][nt], 0, 0, 0);
            }
        }
    }

    int m0 = by * 128, n0 = bx * 64;
#pragma unroll
    for (int mt = 0; mt < 4; mt++)
#pragma unroll
        for (int i = 0; i < 4; i++) {
            int row = m0 + wm * 64 + mt * 16 + quad * 4 + i;
            float* yr = &Yt[(size_t)row * N_ + n0 + wn * 32 + lcol];
#pragma unroll
            for (int nt = 0; nt < 2; nt++) yr[nt * 16] = acc[mt][nt][i];
        }
}

static __device__ __forceinline__ void gemm_f_core(const unsigned short* __restrict__ Wsp,
                                                   const unsigned short* __restrict__ Bht,
                                                   const unsigned short* __restrict__ Blt,
                                                   float* __restrict__ Yt,
                                                   const float* __restrict__ bnp,
                                                   int bx, int by, int tid) {
    int l = tid & 63, wave = tid >> 6;
    int wm = wave >> 1, wn = wave & 1;
    int lcol = l & 15, quad = l >> 4;

    f32x4 acc[4][2];
#pragma unroll
    for (int i = 0; i < 4; i++)
#pragma unroll
        for (int j = 0; j < 2; j++) acc[i][j] = (f32x4){0.f, 0.f, 0.f, 0.f};

#pragma unroll 2
    for (int k32 = 0; k32 < 8; k32++) {
        bf16x8 bh[2], bl[2];
#pragma unroll
        for (int nt = 0; nt < 2; nt++) {
            size_t bpos = ((size_t)((bx * 4 + wn * 2 + nt) * 8 + k32)) * 512 + l * 8;
            bh[nt] = *(const bf16x8*)&Bht[bpos];
            bl[nt] = *(const bf16x8*)&Blt[bpos];
        }
#pragma unroll
        for (int s = 0; s < 3; s++) {
            const unsigned short* Ws = Wsp + (size_t)s * 65536;
#pragma unroll
            for (int mt = 0; mt < 4; mt++) {
                bf16x8 afr = *(const bf16x8*)&Ws[((size_t)((by * 8 + wm * 4 + mt) * 8 + k32)) * 512 + l * 8];
#pragma unroll
                for (int nt = 0; nt < 2; nt++)
                    acc[mt][nt] = __builtin_amdgcn_mfma_f32_16x16x32_bf16(
                        afr, bh[nt], acc[mt][nt], 0, 0, 0);
                if (s < 2) {
#pragma unroll
                    for (int nt = 0; nt < 2; nt++)
                        acc[mt][nt] = __builtin_amdgcn_mfma_f32_16x16x32_bf16(
                            afr, bl[nt], acc[mt][nt], 0, 0, 0);
                }
            }
        }
    }

    int m0 = by * 128, n0 = bx * 64;
#pragma unroll
    for (int mt = 0; mt < 4; mt++)
#pragma unroll
        for (int i = 0; i < 4; i++) {
            int row = m0 + wm * 64 + mt * 16 + quad * 4 + i;
            float i1 = bnp[1024 + row] / sqrtf(bnp[1024 + 768 + row] + EPSB);
            float b1 = bnp[1024 + 256 + row], m1 = bnp[1024 + 512 + row];
            float i2 = bnp[2048 + row] / sqrtf(bnp[2048 + 768 + row] + EPSB);
            float b2 = bnp[2048 + 256 + row], m2 = bnp[2048 + 512 + row];
            float* yr = &Yt[(size_t)row * N_ + n0 + wn * 32 + lcol];
#pragma unroll
            for (int nt = 0; nt < 2; nt++)
                yr[nt * 16] = ((acc[mt][nt][i] - m1) * i1 + b1 - m2) * i2 + b2;
        }
}

// Single-branch wrappers (p chain). Grid (64, 2, 8).
__global__ __launch_bounds__(256) void gemm_s2(const unsigned short* __restrict__ Wsp,
                                               const unsigned short* __restrict__ ST,
                                               float* __restrict__ Y) {
    int t = blockIdx.z;
    gemm_s_core(Wsp, ST + (size_t)t * CN_, Y + (size_t)t * CN_,
                blockIdx.x, blockIdx.y, threadIdx.x);
}
__global__ __launch_bounds__(256) void gemm_f2(const unsigned short* __restrict__ Wsp,
                                               const unsigned short* __restrict__ BhT,
                                               const unsigned short* __restrict__ BlT,
                                               float* __restrict__ Y,
                                               const float* __restrict__ bnp) {
    int t = blockIdx.z;
    gemm_f_core(Wsp, BhT + (size_t)t * CN_, BlT + (size_t)t * CN_,
                Y + (size_t)t * CN_, bnp, blockIdx.x, blockIdx.y, threadIdx.x);
}

// Three-branch mega-dispatch wrappers. by: br = by>>1, m-half = by&1.
struct GSArgs { const unsigned short* W[3]; const unsigned short* ST; float* F[3]; };
__global__ __launch_bounds__(256) void gemm_s3(GSArgs a) {
    int t = blockIdx.z;
    int br = blockIdx.y >> 1, byl = blockIdx.y & 1;
    gemm_s_core(a.W[br], a.ST + (size_t)t * CN_, a.F[br] + (size_t)t * CN_,
                blockIdx.x, byl, threadIdx.x);
}
struct GFArgs {
    const unsigned short* W[3];
    const unsigned short* Ph[3];
    const unsigned short* Pl[3];
    float* F[3];
    const float* bn[3];
};
__global__ __launch_bounds__(256) void gemm_f3(GFArgs a) {
    int t = blockIdx.z;
    int br = blockIdx.y >> 1, byl = blockIdx.y & 1;
    gemm_f_core(a.W[br], a.Ph[br] + (size_t)t * CN_, a.Pl[br] + (size_t)t * CN_,
                a.F[br] + (size_t)t * CN_, a.bn[br], blockIdx.x, byl, threadIdx.x);
}

// ---------------------------------------------------------------------------
// Bitpacked kv: kv[t,h,d,e] = sum_w popcount(K & V).  Exact integer counts.
__global__ __launch_bounds__(1024) void attn_kv_bp(const u64* __restrict__ Kbp,
                                                   const u64* __restrict__ Vbp,
                                                   float* __restrict__ kvbuf) {
    int th = blockIdx.x;
    int t = th >> 3, h = th & 7;
    const u64* kb = Kbp + ((size_t)t * C_ + h * 32) * 64;
    const u64* vb = Vbp + ((size_t)t * C_ + h * 32) * 64;
    __shared__ u64 ks[32][65];
    __shared__ u64 vs[32][65];
    int tid = threadIdx.x;
    {
        int r = tid >> 5, w2 = (tid & 31) * 2;
        ks[r][w2] = kb[r * 64 + w2];     ks[r][w2 + 1] = kb[r * 64 + w2 + 1];
        vs[r][w2] = vb[r * 64 + w2];     vs[r][w2 + 1] = vb[r * 64 + w2 + 1];
    }
    __syncthreads();
    int d = tid >> 5, e = tid & 31;
    int cnt = 0;
#pragma unroll
    for (int w = 0; w < 64; w++)
        cnt += __popcll(ks[d][w] & vs[e][w]);
    kvbuf[(size_t)th * 1024 + d * 32 + e] = (float)cnt;
}

// ---------------------------------------------------------------------------
// FUSED: o = scale * q.kv  +  LIF(o)  +  fragment layout for the p-GEMM.
__global__ __launch_bounds__(256) void attn_olif(const unsigned char* __restrict__ q,
                                                 const float* __restrict__ kvbuf,
                                                 unsigned short* __restrict__ ST) {
    int h = blockIdx.y;
    int nb = blockIdx.x * 128;
    int tid = threadIdx.x;
    int nj = tid & 127, eh = tid >> 7;
    int n = nb + nj;
    __shared__ float kvs[1024];
    const float scale = 0.17677669529663687f;
    float v[16];
#pragma unroll
    for (int e = 0; e < 16; e++) v[e] = 0.f;
    size_t posbase = ((size_t)((n >> 4) * 8 + h)) * 512 + (size_t)(n & 15) * 8;
    int quad0 = 2 * eh;
#pragma unroll
    for (int t = 0; t < T_; t++) {
        for (int i = tid; i < 1024; i += 256)
            kvs[i] = kvbuf[(size_t)(t * 8 + h) * 1024 + i];
        __syncthreads();
        float acc[16];
#pragma unroll
        for (int e = 0; e < 16; e++) acc[e] = 0.f;
        const unsigned char* qb = q + (size_t)t * CN_ + (size_t)(h * 32) * N_ + n;
#pragma unroll 4
        for (int d = 0; d < 32; d++) {
            float qd = (float)qb[(size_t)d * N_];
#pragma unroll
            for (int e = 0; e < 16; e++)
                acc[e] += qd * kvs[d * 32 + eh * 16 + e];
        }
        bf16x8 w0, w1;
#pragma unroll
        for (int e = 0; e < 16; e++) {
            float o = acc[e] * scale;
            v[e] = v[e] + (o - v[e]) / 2.0f;
            int s = (v[e] - 1.0f >= 0.f) ? 1 : 0;
            short bits = s ? (short)0x3F80 : (short)0;
            if (e < 8) w0[e] = bits; else w1[e - 8] = bits;
            if (s) v[e] = 0.f;
        }
        unsigned short* Stt = ST + (size_t)t * CN_;
        *(bf16x8*)&Stt[posbase + (size_t)(quad0 * 16) * 8] = w0;
        *(bf16x8*)&Stt[posbase + (size_t)((quad0 + 1) * 16) * 8] = w1;
        __syncthreads();
    }
}

// ---------------------------------------------------------------------------
extern "C" void kernel_launch(void* const* d_in, const int* in_sizes, int n_in,
                              void* d_out, int out_size, void* d_ws, size_t ws_size,
                              hipStream_t stream) {
    const float* x = (const float*)d_in[0];
    const float* q_w1 = (const float*)d_in[1];
    const float* q_dw = (const float*)d_in[2];
    const float* q_pw = (const float*)d_in[3];
    const float* q_bn = (const float*)d_in[4];
    const float* k_w1 = (const float*)d_in[5];
    const float* k_dw = (const float*)d_in[6];
    const float* k_pw = (const float*)d_in[7];
    const float* k_bn = (const float*)d_in[8];
    const float* v_w1 = (const float*)d_in[9];
    const float* v_dw = (const float*)d_in[10];
    const float* v_pw = (const float*)d_in[11];
    const float* v_bn = (const float*)d_in[12];
    const float* p_w1 = (const float*)d_in[13];
    const float* p_dw = (const float*)d_in[14];
    const float* p_pw = (const float*)d_in[15];
    const float* p_bn = (const float*)d_in[16];

    const size_t SZ = (size_t)T_ * CN_;   // 8,388,608 elements
    float* out = (float*)d_out;           // p-chain fp32 scratch + final output
    float* F0 = (float*)d_ws;             // branch fp32 buffers (33.5 MB each)
    float* F1 = F0 + SZ;
    float* F2 = F1 + SZ;
    float* P0 = F2 + SZ;                  // bf16 pair buffers (hi|lo in one 33.5MB)
    float* P1 = P0 + SZ;
    float* P2 = P1 + SZ;
    float* bufKV = P2 + SZ;               // 65,536 floats
    unsigned char* xs = (unsigned char*)(bufKV + 65536);   // (unused spare)
    unsigned char* sq = xs + SZ;                           // u8 spikes (q)
    u64* kbp = (u64*)(sq + SZ);
    u64* vbp = kbp + (SZ >> 6);
    unsigned short* wspA = (unsigned short*)(vbp + (SZ >> 6));  // 8*3*65536
    unsigned short* ST = wspA + 8 * 3 * 65536;                  // SZ shorts
    // ws total: ~240.4 MB (<256MiB)

    unsigned short* P0h = (unsigned short*)P0; unsigned short* P0l = P0h + SZ;
    unsigned short* P1h = (unsigned short*)P1; unsigned short* P1l = P1h + SZ;
    unsigned short* P2h = (unsigned short*)P2; unsigned short* P2l = P2h + SZ;

    WPtrs wp;
    wp.w[0] = q_w1; wp.w[1] = q_pw; wp.w[2] = k_w1; wp.w[3] = k_pw;
    wp.w[4] = v_w1; wp.w[5] = v_pw; wp.w[6] = p_w1; wp.w[7] = p_pw;
    split_w<<<dim3(256, 8), dim3(256), 0, stream>>>(wp, wspA);
    const size_t WS3 = 3 * 65536;

    // x -> LIF -> spike fragments (one fused dispatch)
    lif_x_frag<<<dim3(N_ / 32, C_ / 8), dim3(256), 0, stream>>>(x, ST);

    // q,k,v first GEMMs in one dispatch (3072 blocks = 12/CU queued)
    GSArgs gs;
    gs.W[0] = wspA + 0 * WS3; gs.W[1] = wspA + 2 * WS3; gs.W[2] = wspA + 4 * WS3;
    gs.ST = ST; gs.F[0] = F0; gs.F[1] = F1; gs.F[2] = F2;
    gemm_s3<<<dim3(N_ / 64, 6, T_), dim3(256), 0, stream>>>(gs);

    // q,k,v dw+BN+split in one dispatch
    DArgs da;
    da.F[0] = F0; da.F[1] = F1; da.F[2] = F2;
    da.dw[0] = q_dw; da.dw[1] = k_dw; da.dw[2] = v_dw;
    da.bn[0] = q_bn; da.bn[1] = k_bn; da.bn[2] = v_bn;
    da.Ph[0] = P0h; da.Ph[1] = P1h; da.Ph[2] = P2h;
    da.Pl[0] = P0l; da.Pl[1] = P1l; da.Pl[2] = P2l;
    dw3<<<dim3(16, 32, 3 * T_), dim3(256), 0, stream>>>(da);

    // q,k,v second GEMMs in one dispatch
    GFArgs gf;
    gf.W[0] = wspA + 1 * WS3; gf.W[1] = wspA + 3 * WS3; gf.W[2] = wspA + 5 * WS3;
    gf.Ph[0] = P0h; gf.Ph[1] = P1h; gf.Ph[2] = P2h;
    gf.Pl[0] = P0l; gf.Pl[1] = P1l; gf.Pl[2] = P2l;
    gf.F[0] = F0; gf.F[1] = F1; gf.F[2] = F2;
    gf.bn[0] = q_bn; gf.bn[1] = k_bn; gf.bn[2] = v_bn;
    gemm_f3<<<dim3(N_ / 64, 6, T_), dim3(256), 0, stream>>>(gf);

    // q,k,v LIFs in one dispatch (q -> u8, k/v -> bitpacked)
    LArgs la;
    la.F[0] = F0; la.F[1] = F1; la.F[2] = F2;
    la.sq = sq; la.kbp = kbp; la.vbp = vbp;
    lif3<<<dim3(CN_ / 256, 3), dim3(256), 0, stream>>>(la);

    // attention: exact popcount kv, then fused o+LIF+fragments -> ST
    attn_kv_bp<<<dim3(64), dim3(1024), 0, stream>>>(kbp, vbp, bufKV);
    attn_olif<<<dim3(N_ / 128, 8), dim3(256), 0, stream>>>(sq, bufKV, ST);

    // p branch: gemm1 -> out (fp32), fused dw+split -> P0 pair, gemm2 -> out
    gemm_s2<<<dim3(N_ / 64, 2, T_), dim3(256), 0, stream>>>(wspA + 6 * WS3, ST, out);
    dw_bn_split<<<dim3(16, 32, T_), dim3(256), 0, stream>>>(out, p_dw, p_bn, P0h, P0l);
    gemm_f2<<<dim3(N_ / 64, 2, T_), dim3(256), 0, stream>>>(wspA + 7 * WS3, P0h, P0l, out, p_bn);
}

// Round 14
// 442.916 us; speedup vs baseline: 1.2444x; 1.2444x over previous
//
#include <hip/hip_runtime.h>
#include <hip/hip_bf16.h>
#include <math.h>

// Problem constants: B(=T)=8, C=256, H=W=64, N=4096, heads=8, d=32.
#define T_ 8
#define C_ 256
#define N_ 4096          // H*W
#define CN_ (C_ * N_)    // 1048576 elements per timestep
#define EPSB 1e-5f

typedef unsigned long long u64;
typedef unsigned int u32;
typedef short bf16x8 __attribute__((ext_vector_type(8)));
typedef float f32x4 __attribute__((ext_vector_type(4)));

static __device__ __forceinline__ unsigned short f2bf(float f) {
    __hip_bfloat16 h = __float2bfloat16(f);   // RTNE
    return *(unsigned short*)&h;
}
static __device__ __forceinline__ float bf2f(unsigned short u) {
    u32 x = (u32)u << 16;                     // exact widen
    return *(float*)&x;
}

// Fragment tiling: a 16(row) x 32(k) tile stored as [lane 64][8 shorts],
// lane = ((k>>3)&3)*16 + (row&15), j = k&7. Tile stride 512 shorts.
// pos(n,k) = ((n>>4)*8 + (k>>5))*512 + (((k>>3)&3)*16 + (n&15))*8 + (k&7).

// ---------------------------------------------------------------------------
// FUSED: LIF(x) + fragment layout. Block = 8-channel octet x 32 n.
__global__ __launch_bounds__(256) void lif_x_frag(const float* __restrict__ X,
                                                  unsigned short* __restrict__ ST) {
    int nb = blockIdx.x * 32;
    int c0 = blockIdx.y * 8;
    int tid = threadIdx.x;
    int nj = tid & 31, ci = tid >> 5;
    size_t base = (size_t)(c0 + ci) * N_ + nb + nj;
    __shared__ unsigned short Ls[8][34];
    int k32 = c0 >> 5, quad = (c0 >> 3) & 3;
    float v = 0.f;
#pragma unroll
    for (int t = 0; t < T_; t++) {
        float xt = X[(size_t)t * CN_ + base];
        v = v + (xt - v) / 2.0f;
        int s = (v - 1.0f >= 0.f) ? 1 : 0;
        Ls[ci][nj] = s ? (unsigned short)0x3F80 : (unsigned short)0;
        if (s) v = 0.f;
        __syncthreads();
        if (tid < 32) {
            int np = nb + tid;
            bf16x8 bs;
#pragma unroll
            for (int j = 0; j < 8; j++) bs[j] = (short)Ls[j][tid];
            *(bf16x8*)&ST[(size_t)t * CN_ +
                ((size_t)((np >> 4) * 8 + k32)) * 512 + (quad * 16 + (np & 15)) * 8] = bs;
        }
        __syncthreads();
    }
}

// ---------------------------------------------------------------------------
// Branch-indexed LIF: br 0 -> u8 spikes (q), br 1/2 -> bitpacked (k, v).
struct LArgs {
    const float* F[3];
    unsigned char* sq;
    u64* kbp;
    u64* vbp;
};
__global__ __launch_bounds__(256) void lif3(LArgs a) {
    int br = blockIdx.y;
    int idx = blockIdx.x * 256 + threadIdx.x;
    const float* X = a.F[br];
    int lane = threadIdx.x & 63;
    u64* BP = (br == 1) ? a.kbp : a.vbp;
    float v = 0.f;
#pragma unroll
    for (int t = 0; t < T_; t++) {
        float xt = X[(size_t)t * CN_ + idx];
        v = v + (xt - v) / 2.0f;
        int s = (v - 1.0f >= 0.f) ? 1 : 0;
        if (br == 0) {
            a.sq[(size_t)t * CN_ + idx] = (unsigned char)s;
        } else {
            u64 mask = __ballot(s);
            if (lane == 0) BP[((size_t)t * CN_ + idx) >> 6] = mask;
        }
        if (s) v = 0.f;
    }
}

// ---------------------------------------------------------------------------
// Exact 3-way bf16 split of the eight 256x256 weights -> A-fragment layout.
struct WPtrs { const float* w[8]; };
__global__ __launch_bounds__(256) void split_w(WPtrs p, unsigned short* __restrict__ out) {
    int mat = blockIdx.y;
    int idx = blockIdx.x * 256 + threadIdx.x;   // = m*256 + k
    int m = idx >> 8, k = idx & 255;
    float w = p.w[mat][idx];
    unsigned short h1 = f2bf(w);
    float f1 = bf2f(h1);
    unsigned short h2 = f2bf(w - f1);
    unsigned short h3 = f2bf(w - f1 - bf2f(h2));   // exact: 8+8+8 bits
    int lane = ((k >> 3) & 3) * 16 + (m & 15);
    size_t pos = ((size_t)(((m >> 4) * 8 + (k >> 5)) * 64 + lane)) * 8 + (k & 7);
    size_t base = (size_t)mat * 3 * 65536;
    out[base + pos] = h1;
    out[base + 65536 + pos] = h2;
    out[base + 2 * 65536 + pos] = h3;
}

// ---------------------------------------------------------------------------
// Core of the fused dw+BN+pad+split (R9-verified arithmetic), parameterized.
static __device__ __forceinline__ void dw_body(const float* __restrict__ Yt,
                                               const float* __restrict__ dw,
                                               const float* __restrict__ bnp,
                                               unsigned short* __restrict__ Bh,
                                               unsigned short* __restrict__ Bl,
                                               int y0, int cg, int tid) {
    int c0 = cg * 8;
    __shared__ float L[8][6][68];
    __shared__ float invs[8], bs_[8], ms_[8], pads_[8];

    if (tid < 8) {
        int c = c0 + tid;
        float w = bnp[c], b = bnp[256 + c], m = bnp[512 + c], var = bnp[768 + c];
        float sq = sqrtf(var + EPSB);
        invs[tid] = w / sq;
        bs_[tid] = b;
        ms_[tid] = m;
        pads_[tid] = b - (m * w) / sq;
    }
    __syncthreads();

    for (int i = tid; i < 8 * 6 * 66; i += 256) {
        int c = i / 396;
        int rem = i - c * 396;
        int row = rem / 66, col = rem - row * 66;
        int gy = y0 - 1 + row, gx = col - 1;
        float val;
        if (gy < 0 || gy > 63 || gx < 0 || gx > 63) val = pads_[c];
        else val = (Yt[(size_t)(c0 + c) * N_ + gy * 64 + gx] - ms_[c]) * invs[c] + bs_[c];
        L[c][row][col] = val;
    }
    __syncthreads();

    int x = tid & 63, ry = tid >> 6;
    int n = (y0 + ry) * 64 + x;

    bf16x8 hi, lo;
#pragma unroll
    for (int j = 0; j < 8; j++) {
        const float* dwc = dw + (c0 + j) * 9;
        float a = 0.f;
#pragma unroll
        for (int dy = 0; dy < 3; dy++)
#pragma unroll
            for (int dx = 0; dx < 3; dx++)
                a += dwc[dy * 3 + dx] * L[j][ry + dy][x + dx];
        unsigned short h = f2bf(a);
        hi[j] = (short)h;
        lo[j] = (short)f2bf(a - bf2f(h));
    }
    size_t pos = ((size_t)((n >> 4) * 8 + (cg >> 2))) * 512 +
                 (size_t)(((cg & 3) * 16 + (n & 15)) * 8);
    *(bf16x8*)&Bh[pos] = hi;
    *(bf16x8*)&Bl[pos] = lo;
}

// Single-branch version (p chain).
__global__ __launch_bounds__(256) void dw_bn_split(const float* __restrict__ Yin,
                                                   const float* __restrict__ dw,
                                                   const float* __restrict__ bnp,
                                                   unsigned short* __restrict__ BhT,
                                                   unsigned short* __restrict__ BlT) {
    int t = blockIdx.z;
    dw_body(Yin + (size_t)t * CN_, dw, bnp,
            BhT + (size_t)t * CN_, BlT + (size_t)t * CN_,
            blockIdx.x * 4, blockIdx.y, threadIdx.x);
}

// Three-branch version (q,k,v in one dispatch). z: br = z>>3, t = z&7.
struct DArgs {
    const float* F[3];
    const float* dw[3];
    const float* bn[3];
    unsigned short* Ph[3];
    unsigned short* Pl[3];
};
__global__ __launch_bounds__(256) void dw3(DArgs a) {
    int br = blockIdx.z >> 3, t = blockIdx.z & 7;
    dw_body(a.F[br] + (size_t)t * CN_, a.dw[br], a.bn[br],
            a.Ph[br] + (size_t)t * CN_, a.Pl[br] + (size_t)t * CN_,
            blockIdx.x * 4, blockIdx.y, threadIdx.x);
}

// ---------------------------------------------------------------------------
// R11-verified LDS-free MFMA GEMM cores (128x128 tile, 4 waves 2x2).
// unroll 4 on the K-loop: deeper load pipelining (no barriers, no LDS).
static __device__ __forceinline__ void gemm_s_core(const unsigned short* __restrict__ Wsp,
                                                   const unsigned short* __restrict__ Bt,
                                                   float* __restrict__ Yt,
                                                   int bx, int by, int tid) {
    int l = tid & 63, wave = tid >> 6;
    int wm = wave >> 1, wn = wave & 1;
    int lcol = l & 15, quad = l >> 4;

    f32x4 acc[4][4];
#pragma unroll
    for (int i = 0; i < 4; i++)
#pragma unroll
        for (int j = 0; j < 4; j++) acc[i][j] = (f32x4){0.f, 0.f, 0.f, 0.f};

#pragma unroll 4
    for (int k32 = 0; k32 < 8; k32++) {
        bf16x8 bfr[4];
#pragma unroll
        for (int nt = 0; nt < 4; nt++)
            bfr[nt] = *(const bf16x8*)&Bt[((size_t)((bx * 8 + wn * 4 + nt) * 8 + k32)) * 512 + l * 8];
#pragma unroll
        for (int s = 0; s < 3; s++) {
            const unsigned short* Ws = Wsp + (size_t)s * 65536;
#pragma unroll
            for (int mt = 0; mt < 4; mt++) {
                bf16x8 afr = *(const bf16x8*)&Ws[((size_t)((by * 8 + wm * 4 + mt) * 8 + k32)) * 512 + l * 8];
#pragma unroll
                for (int nt = 0; nt < 4; nt++)
                    acc[mt][nt] = __builtin_amdgcn_mfma_f32_16x16x32_bf16(
                        afr, bfr[nt], acc[mt][nt], 0, 0, 0);
            }
        }
    }

    int m0 = by * 128, n0 = bx * 128;
#pragma unroll
    for (int mt = 0; mt < 4; mt++)
#pragma unroll
        for (int i = 0; i < 4; i++) {
            int row = m0 + wm * 64 + mt * 16 + quad * 4 + i;
            float* yr = &Yt[(size_t)row * N_ + n0 + wn * 64 + lcol];
#pragma unroll
            for (int nt = 0; nt < 4; nt++) yr[nt * 16] = acc[mt][nt][i];
        }
}

static __device__ __forceinline__ void gemm_f_core(const unsigned short* __restrict__ Wsp,
                                                   const unsigned short* __restrict__ Bht,
                                                   const unsigned short* __restrict__ Blt,
                                                   float* __restrict__ Yt,
                                                   const float* __restrict__ bnp,
                                                   int bx, int by, int tid) {
    int l = tid & 63, wave = tid >> 6;
    int wm = wave >> 1, wn = wave & 1;
    int lcol = l & 15, quad = l >> 4;

    f32x4 acc[4][4];
#pragma unroll
    for (int i = 0; i < 4; i++)
#pragma unroll
        for (int j = 0; j < 4; j++) acc[i][j] = (f32x4){0.f, 0.f, 0.f, 0.f};

#pragma unroll 4
    for (int k32 = 0; k32 < 8; k32++) {
        bf16x8 bh[4], bl[4];
#pragma unroll
        for (int nt = 0; nt < 4; nt++) {
            size_t bpos = ((size_t)((bx * 8 + wn * 4 + nt) * 8 + k32)) * 512 + l * 8;
            bh[nt] = *(const bf16x8*)&Bht[bpos];
            bl[nt] = *(const bf16x8*)&Blt[bpos];
        }
#pragma unroll
        for (int s = 0; s < 3; s++) {
            const unsigned short* Ws = Wsp + (size_t)s * 65536;
#pragma unroll
            for (int mt = 0; mt < 4; mt++) {
                bf16x8 afr = *(const bf16x8*)&Ws[((size_t)((by * 8 + wm * 4 + mt) * 8 + k32)) * 512 + l * 8];
#pragma unroll
                for (int nt = 0; nt < 4; nt++)
                    acc[mt][nt] = __builtin_amdgcn_mfma_f32_16x16x32_bf16(
                        afr, bh[nt], acc[mt][nt], 0, 0, 0);
                if (s < 2) {
#pragma unroll
                    for (int nt = 0; nt < 4; nt++)
                        acc[mt][nt] = __builtin_amdgcn_mfma_f32_16x16x32_bf16(
                            afr, bl[nt], acc[mt][nt], 0, 0, 0);
                }
            }
        }
    }

    int m0 = by * 128, n0 = bx * 128;
#pragma unroll
    for (int mt = 0; mt < 4; mt++)
#pragma unroll
        for (int i = 0; i < 4; i++) {
            int row = m0 + wm * 64 + mt * 16 + quad * 4 + i;
            float i1 = bnp[1024 + row] / sqrtf(bnp[1024 + 768 + row] + EPSB);
            float b1 = bnp[1024 + 256 + row], m1 = bnp[1024 + 512 + row];
            float i2 = bnp[2048 + row] / sqrtf(bnp[2048 + 768 + row] + EPSB);
            float b2 = bnp[2048 + 256 + row], m2 = bnp[2048 + 512 + row];
            float* yr = &Yt[(size_t)row * N_ + n0 + wn * 64 + lcol];
#pragma unroll
            for (int nt = 0; nt < 4; nt++)
                yr[nt * 16] = ((acc[mt][nt][i] - m1) * i1 + b1 - m2) * i2 + b2;
        }
}

// Single-branch wrappers (p chain).
__global__ __launch_bounds__(256) void gemm_s2(const unsigned short* __restrict__ Wsp,
                                               const unsigned short* __restrict__ ST,
                                               float* __restrict__ Y) {
    int t = blockIdx.z;
    gemm_s_core(Wsp, ST + (size_t)t * CN_, Y + (size_t)t * CN_,
                blockIdx.x, blockIdx.y, threadIdx.x);
}
__global__ __launch_bounds__(256) void gemm_f2(const unsigned short* __restrict__ Wsp,
                                               const unsigned short* __restrict__ BhT,
                                               const unsigned short* __restrict__ BlT,
                                               float* __restrict__ Y,
                                               const float* __restrict__ bnp) {
    int t = blockIdx.z;
    gemm_f_core(Wsp, BhT + (size_t)t * CN_, BlT + (size_t)t * CN_,
                Y + (size_t)t * CN_, bnp, blockIdx.x, blockIdx.y, threadIdx.x);
}

// Three-branch mega-dispatch wrappers. by: br = by>>1, m-half = by&1.
struct GSArgs { const unsigned short* W[3]; const unsigned short* ST; float* F[3]; };
__global__ __launch_bounds__(256) void gemm_s3(GSArgs a) {
    int t = blockIdx.z;
    int br = blockIdx.y >> 1, byl = blockIdx.y & 1;
    gemm_s_core(a.W[br], a.ST + (size_t)t * CN_, a.F[br] + (size_t)t * CN_,
                blockIdx.x, byl, threadIdx.x);
}
struct GFArgs {
    const unsigned short* W[3];
    const unsigned short* Ph[3];
    const unsigned short* Pl[3];
    float* F[3];
    const float* bn[3];
};
__global__ __launch_bounds__(256) void gemm_f3(GFArgs a) {
    int t = blockIdx.z;
    int br = blockIdx.y >> 1, byl = blockIdx.y & 1;
    gemm_f_core(a.W[br], a.Ph[br] + (size_t)t * CN_, a.Pl[br] + (size_t)t * CN_,
                a.F[br] + (size_t)t * CN_, a.bn[br], blockIdx.x, byl, threadIdx.x);
}

// ---------------------------------------------------------------------------
// Bitpacked kv: kv[t,h,d,e] = sum_w popcount(K & V).  Exact integer counts.
__global__ __launch_bounds__(1024) void attn_kv_bp(const u64* __restrict__ Kbp,
                                                   const u64* __restrict__ Vbp,
                                                   float* __restrict__ kvbuf) {
    int th = blockIdx.x;
    int t = th >> 3, h = th & 7;
    const u64* kb = Kbp + ((size_t)t * C_ + h * 32) * 64;
    const u64* vb = Vbp + ((size_t)t * C_ + h * 32) * 64;
    __shared__ u64 ks[32][65];
    __shared__ u64 vs[32][65];
    int tid = threadIdx.x;
    {
        int r = tid >> 5, w2 = (tid & 31) * 2;
        ks[r][w2] = kb[r * 64 + w2];     ks[r][w2 + 1] = kb[r * 64 + w2 + 1];
        vs[r][w2] = vb[r * 64 + w2];     vs[r][w2 + 1] = vb[r * 64 + w2 + 1];
    }
    __syncthreads();
    int d = tid >> 5, e = tid & 31;
    int cnt = 0;
#pragma unroll
    for (int w = 0; w < 64; w++)
        cnt += __popcll(ks[d][w] & vs[e][w]);
    kvbuf[(size_t)th * 1024 + d * 32 + e] = (float)cnt;
}

// ---------------------------------------------------------------------------
// FUSED: o = scale * q.kv  +  LIF(o)  +  fragment layout for the p-GEMM.
__global__ __launch_bounds__(256) void attn_olif(const unsigned char* __restrict__ q,
                                                 const float* __restrict__ kvbuf,
                                                 unsigned short* __restrict__ ST) {
    int h = blockIdx.y;
    int nb = blockIdx.x * 128;
    int tid = threadIdx.x;
    int nj = tid & 127, eh = tid >> 7;
    int n = nb + nj;
    __shared__ float kvs[1024];
    const float scale = 0.17677669529663687f;
    float v[16];
#pragma unroll
    for (int e = 0; e < 16; e++) v[e] = 0.f;
    size_t posbase = ((size_t)((n >> 4) * 8 + h)) * 512 + (size_t)(n & 15) * 8;
    int quad0 = 2 * eh;
#pragma unroll
    for (int t = 0; t < T_; t++) {
        for (int i = tid; i < 1024; i += 256)
            kvs[i] = kvbuf[(size_t)(t * 8 + h) * 1024 + i];
        __syncthreads();
        float acc[16];
#pragma unroll
        for (int e = 0; e < 16; e++) acc[e] = 0.f;
        const unsigned char* qb = q + (size_t)t * CN_ + (size_t)(h * 32) * N_ + n;
#pragma unroll 4
        for (int d = 0; d < 32; d++) {
            float qd = (float)qb[(size_t)d * N_];
#pragma unroll
            for (int e = 0; e < 16; e++)
                acc[e] += qd * kvs[d * 32 + eh * 16 + e];
        }
        bf16x8 w0, w1;
#pragma unroll
        for (int e = 0; e < 16; e++) {
            float o = acc[e] * scale;
            v[e] = v[e] + (o - v[e]) / 2.0f;
            int s = (v[e] - 1.0f >= 0.f) ? 1 : 0;
            short bits = s ? (short)0x3F80 : (short)0;
            if (e < 8) w0[e] = bits; else w1[e - 8] = bits;
            if (s) v[e] = 0.f;
        }
        unsigned short* Stt = ST + (size_t)t * CN_;
        *(bf16x8*)&Stt[posbase + (size_t)(quad0 * 16) * 8] = w0;
        *(bf16x8*)&Stt[posbase + (size_t)((quad0 + 1) * 16) * 8] = w1;
        __syncthreads();
    }
}

// ---------------------------------------------------------------------------
extern "C" void kernel_launch(void* const* d_in, const int* in_sizes, int n_in,
                              void* d_out, int out_size, void* d_ws, size_t ws_size,
                              hipStream_t stream) {
    const float* x = (const float*)d_in[0];
    const float* q_w1 = (const float*)d_in[1];
    const float* q_dw = (const float*)d_in[2];
    const float* q_pw = (const float*)d_in[3];
    const float* q_bn = (const float*)d_in[4];
    const float* k_w1 = (const float*)d_in[5];
    const float* k_dw = (const float*)d_in[6];
    const float* k_pw = (const float*)d_in[7];
    const float* k_bn = (const float*)d_in[8];
    const float* v_w1 = (const float*)d_in[9];
    const float* v_dw = (const float*)d_in[10];
    const float* v_pw = (const float*)d_in[11];
    const float* v_bn = (const float*)d_in[12];
    const float* p_w1 = (const float*)d_in[13];
    const float* p_dw = (const float*)d_in[14];
    const float* p_pw = (const float*)d_in[15];
    const float* p_bn = (const float*)d_in[16];

    const size_t SZ = (size_t)T_ * CN_;   // 8,388,608 elements
    float* out = (float*)d_out;           // p-chain fp32 scratch + final output
    float* F0 = (float*)d_ws;             // branch fp32 buffers (33.5 MB each)
    float* F1 = F0 + SZ;
    float* F2 = F1 + SZ;
    float* P0 = F2 + SZ;                  // bf16 pair buffers (hi|lo in one 33.5MB)
    float* P1 = P0 + SZ;
    float* P2 = P1 + SZ;
    float* bufKV = P2 + SZ;               // 65,536 floats
    unsigned char* xs = (unsigned char*)(bufKV + 65536);   // (unused spare)
    unsigned char* sq = xs + SZ;                           // u8 spikes (q)
    u64* kbp = (u64*)(sq + SZ);
    u64* vbp = kbp + (SZ >> 6);
    unsigned short* wspA = (unsigned short*)(vbp + (SZ >> 6));  // 8*3*65536
    unsigned short* ST = wspA + 8 * 3 * 65536;                  // SZ shorts
    // ws total: ~240.4 MB (<256MiB)

    unsigned short* P0h = (unsigned short*)P0; unsigned short* P0l = P0h + SZ;
    unsigned short* P1h = (unsigned short*)P1; unsigned short* P1l = P1h + SZ;
    unsigned short* P2h = (unsigned short*)P2; unsigned short* P2l = P2h + SZ;

    WPtrs wp;
    wp.w[0] = q_w1; wp.w[1] = q_pw; wp.w[2] = k_w1; wp.w[3] = k_pw;
    wp.w[4] = v_w1; wp.w[5] = v_pw; wp.w[6] = p_w1; wp.w[7] = p_pw;
    split_w<<<dim3(256, 8), dim3(256), 0, stream>>>(wp, wspA);
    const size_t WS3 = 3 * 65536;

    // x -> LIF -> spike fragments (one fused dispatch)
    lif_x_frag<<<dim3(N_ / 32, C_ / 8), dim3(256), 0, stream>>>(x, ST);

    // q,k,v first GEMMs in one dispatch (1536 blocks = 6/CU)
    GSArgs gs;
    gs.W[0] = wspA + 0 * WS3; gs.W[1] = wspA + 2 * WS3; gs.W[2] = wspA + 4 * WS3;
    gs.ST = ST; gs.F[0] = F0; gs.F[1] = F1; gs.F[2] = F2;
    gemm_s3<<<dim3(N_ / 128, 6, T_), dim3(256), 0, stream>>>(gs);

    // q,k,v dw+BN+split in one dispatch
    DArgs da;
    da.F[0] = F0; da.F[1] = F1; da.F[2] = F2;
    da.dw[0] = q_dw; da.dw[1] = k_dw; da.dw[2] = v_dw;
    da.bn[0] = q_bn; da.bn[1] = k_bn; da.bn[2] = v_bn;
    da.Ph[0] = P0h; da.Ph[1] = P1h; da.Ph[2] = P2h;
    da.Pl[0] = P0l; da.Pl[1] = P1l; da.Pl[2] = P2l;
    dw3<<<dim3(16, 32, 3 * T_), dim3(256), 0, stream>>>(da);

    // q,k,v second GEMMs in one dispatch
    GFArgs gf;
    gf.W[0] = wspA + 1 * WS3; gf.W[1] = wspA + 3 * WS3; gf.W[2] = wspA + 5 * WS3;
    gf.Ph[0] = P0h; gf.Ph[1] = P1h; gf.Ph[2] = P2h;
    gf.Pl[0] = P0l; gf.Pl[1] = P1l; gf.Pl[2] = P2l;
    gf.F[0] = F0; gf.F[1] = F1; gf.F[2] = F2;
    gf.bn[0] = q_bn; gf.bn[1] = k_bn; gf.bn[2] = v_bn;
    gemm_f3<<<dim3(N_ / 128, 6, T_), dim3(256), 0, stream>>>(gf);

    // q,k,v LIFs in one dispatch (q -> u8, k/v -> bitpacked)
    LArgs la;
    la.F[0] = F0; la.F[1] = F1; la.F[2] = F2;
    la.sq = sq; la.kbp = kbp; la.vbp = vbp;
    lif3<<<dim3(CN_ / 256, 3), dim3(256), 0, stream>>>(la);

    // attention: exact popcount kv, then fused o+LIF+fragments -> ST
    attn_kv_bp<<<dim3(64), dim3(1024), 0, stream>>>(kbp, vbp, bufKV);
    attn_olif<<<dim3(N_ / 128, 8), dim3(256), 0, stream>>>(sq, bufKV, ST);

    // p branch: gemm1 -> out (fp32), fused dw+split -> P0 pair, gemm2 -> out
    gemm_s2<<<dim3(N_ / 128, C_ / 128, T_), dim3(256), 0, stream>>>(wspA + 6 * WS3, ST, out);
    dw_bn_split<<<dim3(16, 32, T_), dim3(256), 0, stream>>>(out, p_dw, p_bn, P0h, P0l);
    gemm_f2<<<dim3(N_ / 128, C_ / 128, T_), dim3(256), 0, stream>>>(wspA + 7 * WS3, P0h, P0l, out, p_bn);
}

// Round 15
// 413.369 us; speedup vs baseline: 1.3334x; 1.0715x over previous
//
#include <hip/hip_runtime.h>
#include <hip/hip_bf16.h>
#include <math.h>

// Problem constants: B(=T)=8, C=256, H=W=64, N=4096, heads=8, d=32.
#define T_ 8
#define C_ 256
#define N_ 4096          // H*W
#define CN_ (C_ * N_)    // 1048576 elements per timestep
#define EPSB 1e-5f

typedef unsigned long long u64;
typedef unsigned int u32;
typedef short bf16x8 __attribute__((ext_vector_type(8)));
typedef float f32x4 __attribute__((ext_vector_type(4)));

static __device__ __forceinline__ unsigned short f2bf(float f) {
    __hip_bfloat16 h = __float2bfloat16(f);   // RTNE
    return *(unsigned short*)&h;
}
static __device__ __forceinline__ float bf2f(unsigned short u) {
    u32 x = (u32)u << 16;                     // exact widen
    return *(float*)&x;
}

// Async global->LDS, 16B per lane: HW writes lane l at (lds base + l*16),
// per-lane source = g (we pass tile_base + l*16 -> exact tile copy).
typedef const __attribute__((address_space(1))) unsigned int ga_u32;
typedef __attribute__((address_space(3))) unsigned int la_u32;
static __device__ __forceinline__ void gl_lds16(const unsigned short* g,
                                                unsigned short* l_) {
    __builtin_amdgcn_global_load_lds((ga_u32*)g, (la_u32*)l_, 16, 0, 0);
}

// Fragment tiling: a 16(row) x 32(k) tile stored as [lane 64][8 shorts],
// lane = ((k>>3)&3)*16 + (row&15), j = k&7. Tile stride 512 shorts.
// pos(n,k) = ((n>>4)*8 + (k>>5))*512 + (((k>>3)&3)*16 + (n&15))*8 + (k&7).

// ---------------------------------------------------------------------------
// FUSED: LIF(x) + fragment layout. Block = 8-channel octet x 32 n.
__global__ __launch_bounds__(256) void lif_x_frag(const float* __restrict__ X,
                                                  unsigned short* __restrict__ ST) {
    int nb = blockIdx.x * 32;
    int c0 = blockIdx.y * 8;
    int tid = threadIdx.x;
    int nj = tid & 31, ci = tid >> 5;
    size_t base = (size_t)(c0 + ci) * N_ + nb + nj;
    __shared__ unsigned short Ls[8][34];
    int k32 = c0 >> 5, quad = (c0 >> 3) & 3;
    float v = 0.f;
#pragma unroll
    for (int t = 0; t < T_; t++) {
        float xt = X[(size_t)t * CN_ + base];
        v = v + (xt - v) / 2.0f;
        int s = (v - 1.0f >= 0.f) ? 1 : 0;
        Ls[ci][nj] = s ? (unsigned short)0x3F80 : (unsigned short)0;
        if (s) v = 0.f;
        __syncthreads();
        if (tid < 32) {
            int np = nb + tid;
            bf16x8 bs;
#pragma unroll
            for (int j = 0; j < 8; j++) bs[j] = (short)Ls[j][tid];
            *(bf16x8*)&ST[(size_t)t * CN_ +
                ((size_t)((np >> 4) * 8 + k32)) * 512 + (quad * 16 + (np & 15)) * 8] = bs;
        }
        __syncthreads();
    }
}

// ---------------------------------------------------------------------------
// Branch-indexed LIF: br 0 -> u8 spikes (q), br 1/2 -> bitpacked (k, v).
struct LArgs {
    const float* F[3];
    unsigned char* sq;
    u64* kbp;
    u64* vbp;
};
__global__ __launch_bounds__(256) void lif3(LArgs a) {
    int br = blockIdx.y;
    int idx = blockIdx.x * 256 + threadIdx.x;
    const float* X = a.F[br];
    int lane = threadIdx.x & 63;
    u64* BP = (br == 1) ? a.kbp : a.vbp;
    float v = 0.f;
#pragma unroll
    for (int t = 0; t < T_; t++) {
        float xt = X[(size_t)t * CN_ + idx];
        v = v + (xt - v) / 2.0f;
        int s = (v - 1.0f >= 0.f) ? 1 : 0;
        if (br == 0) {
            a.sq[(size_t)t * CN_ + idx] = (unsigned char)s;
        } else {
            u64 mask = __ballot(s);
            if (lane == 0) BP[((size_t)t * CN_ + idx) >> 6] = mask;
        }
        if (s) v = 0.f;
    }
}

// ---------------------------------------------------------------------------
// Exact 3-way bf16 split of the eight 256x256 weights -> A-fragment layout.
struct WPtrs { const float* w[8]; };
__global__ __launch_bounds__(256) void split_w(WPtrs p, unsigned short* __restrict__ out) {
    int mat = blockIdx.y;
    int idx = blockIdx.x * 256 + threadIdx.x;   // = m*256 + k
    int m = idx >> 8, k = idx & 255;
    float w = p.w[mat][idx];
    unsigned short h1 = f2bf(w);
    float f1 = bf2f(h1);
    unsigned short h2 = f2bf(w - f1);
    unsigned short h3 = f2bf(w - f1 - bf2f(h2));   // exact: 8+8+8 bits
    int lane = ((k >> 3) & 3) * 16 + (m & 15);
    size_t pos = ((size_t)(((m >> 4) * 8 + (k >> 5)) * 64 + lane)) * 8 + (k & 7);
    size_t base = (size_t)mat * 3 * 65536;
    out[base + pos] = h1;
    out[base + 65536 + pos] = h2;
    out[base + 2 * 65536 + pos] = h3;
}

// ---------------------------------------------------------------------------
// Core of the fused dw+BN+pad+split (R9-verified arithmetic), parameterized.
static __device__ __forceinline__ void dw_body(const float* __restrict__ Yt,
                                               const float* __restrict__ dw,
                                               const float* __restrict__ bnp,
                                               unsigned short* __restrict__ Bh,
                                               unsigned short* __restrict__ Bl,
                                               int y0, int cg, int tid) {
    int c0 = cg * 8;
    __shared__ float L[8][6][68];
    __shared__ float invs[8], bs_[8], ms_[8], pads_[8];

    if (tid < 8) {
        int c = c0 + tid;
        float w = bnp[c], b = bnp[256 + c], m = bnp[512 + c], var = bnp[768 + c];
        float sq = sqrtf(var + EPSB);
        invs[tid] = w / sq;
        bs_[tid] = b;
        ms_[tid] = m;
        pads_[tid] = b - (m * w) / sq;
    }
    __syncthreads();

    for (int i = tid; i < 8 * 6 * 66; i += 256) {
        int c = i / 396;
        int rem = i - c * 396;
        int row = rem / 66, col = rem - row * 66;
        int gy = y0 - 1 + row, gx = col - 1;
        float val;
        if (gy < 0 || gy > 63 || gx < 0 || gx > 63) val = pads_[c];
        else val = (Yt[(size_t)(c0 + c) * N_ + gy * 64 + gx] - ms_[c]) * invs[c] + bs_[c];
        L[c][row][col] = val;
    }
    __syncthreads();

    int x = tid & 63, ry = tid >> 6;
    int n = (y0 + ry) * 64 + x;

    bf16x8 hi, lo;
#pragma unroll
    for (int j = 0; j < 8; j++) {
        const float* dwc = dw + (c0 + j) * 9;
        float a = 0.f;
#pragma unroll
        for (int dy = 0; dy < 3; dy++)
#pragma unroll
            for (int dx = 0; dx < 3; dx++)
                a += dwc[dy * 3 + dx] * L[j][ry + dy][x + dx];
        unsigned short h = f2bf(a);
        hi[j] = (short)h;
        lo[j] = (short)f2bf(a - bf2f(h));
    }
    size_t pos = ((size_t)((n >> 4) * 8 + (cg >> 2))) * 512 +
                 (size_t)(((cg & 3) * 16 + (n & 15)) * 8);
    *(bf16x8*)&Bh[pos] = hi;
    *(bf16x8*)&Bl[pos] = lo;
}

// Single-branch version (p chain).
__global__ __launch_bounds__(256) void dw_bn_split(const float* __restrict__ Yin,
                                                   const float* __restrict__ dw,
                                                   const float* __restrict__ bnp,
                                                   unsigned short* __restrict__ BhT,
                                                   unsigned short* __restrict__ BlT) {
    int t = blockIdx.z;
    dw_body(Yin + (size_t)t * CN_, dw, bnp,
            BhT + (size_t)t * CN_, BlT + (size_t)t * CN_,
            blockIdx.x * 4, blockIdx.y, threadIdx.x);
}

// Three-branch version (q,k,v in one dispatch). z: br = z>>3, t = z&7.
struct DArgs {
    const float* F[3];
    const float* dw[3];
    const float* bn[3];
    unsigned short* Ph[3];
    unsigned short* Pl[3];
};
__global__ __launch_bounds__(256) void dw3(DArgs a) {
    int br = blockIdx.z >> 3, t = blockIdx.z & 7;
    dw_body(a.F[br] + (size_t)t * CN_, a.dw[br], a.bn[br],
            a.Ph[br] + (size_t)t * CN_, a.Pl[br] + (size_t)t * CN_,
            blockIdx.x * 4, blockIdx.y, threadIdx.x);
}

// ---------------------------------------------------------------------------
// LDS-staged MFMA GEMM cores (128x128 tile, 4 waves 2x2).
// Per k32: stage unique operand tiles into LDS ONCE per block via
// global_load_lds (halves per-CU TA traffic vs LDS-free), then ds_read frags.
// MFMA order per output element identical to R11 -> bit-identical results.
static __device__ __forceinline__ void gemm_s_core(const unsigned short* __restrict__ Wsp,
                                                   const unsigned short* __restrict__ Bt,
                                                   float* __restrict__ Yt,
                                                   int bx, int by, int tid) {
    int l = tid & 63, wave = tid >> 6;
    int wm = wave >> 1, wn = wave & 1;
    int lcol = l & 15, quad = l >> 4;

    __shared__ unsigned short As[24][512];   // [s*8 + mtg], 24KB
    __shared__ unsigned short Bs[8][512];    // [nt], 8KB

    f32x4 acc[4][4];
#pragma unroll
    for (int i = 0; i < 4; i++)
#pragma unroll
        for (int j = 0; j < 4; j++) acc[i][j] = (f32x4){0.f, 0.f, 0.f, 0.f};

    for (int k32 = 0; k32 < 8; k32++) {
        // stage 32 tiles (24 A + 8 B), 8 per wave
#pragma unroll
        for (int i = 0; i < 8; i++) {
            int tau = wave * 8 + i;
            if (tau < 24) {
                int s = tau >> 3, mtg = tau & 7;
                gl_lds16(&Wsp[(size_t)s * 65536 +
                              ((size_t)((by * 8 + mtg) * 8 + k32)) * 512 + l * 8],
                         &As[tau][0]);
            } else {
                int nt = tau - 24;
                gl_lds16(&Bt[((size_t)((bx * 8 + nt) * 8 + k32)) * 512 + l * 8],
                         &Bs[nt][0]);
            }
        }
        __syncthreads();

        bf16x8 bfr[4];
#pragma unroll
        for (int nt = 0; nt < 4; nt++)
            bfr[nt] = *(const bf16x8*)&Bs[wn * 4 + nt][l * 8];
#pragma unroll
        for (int s = 0; s < 3; s++) {
#pragma unroll
            for (int mt = 0; mt < 4; mt++) {
                bf16x8 afr = *(const bf16x8*)&As[s * 8 + wm * 4 + mt][l * 8];
#pragma unroll
                for (int nt = 0; nt < 4; nt++)
                    acc[mt][nt] = __builtin_amdgcn_mfma_f32_16x16x32_bf16(
                        afr, bfr[nt], acc[mt][nt], 0, 0, 0);
            }
        }
        __syncthreads();
    }

    int m0 = by * 128, n0 = bx * 128;
#pragma unroll
    for (int mt = 0; mt < 4; mt++)
#pragma unroll
        for (int i = 0; i < 4; i++) {
            int row = m0 + wm * 64 + mt * 16 + quad * 4 + i;
            float* yr = &Yt[(size_t)row * N_ + n0 + wn * 64 + lcol];
#pragma unroll
            for (int nt = 0; nt < 4; nt++) yr[nt * 16] = acc[mt][nt][i];
        }
}

static __device__ __forceinline__ void gemm_f_core(const unsigned short* __restrict__ Wsp,
                                                   const unsigned short* __restrict__ Bht,
                                                   const unsigned short* __restrict__ Blt,
                                                   float* __restrict__ Yt,
                                                   const float* __restrict__ bnp,
                                                   int bx, int by, int tid) {
    int l = tid & 63, wave = tid >> 6;
    int wm = wave >> 1, wn = wave & 1;
    int lcol = l & 15, quad = l >> 4;

    __shared__ unsigned short As[24][512];   // 24KB
    __shared__ unsigned short Bhs[8][512];   // 8KB
    __shared__ unsigned short Bls[8][512];   // 8KB

    f32x4 acc[4][4];
#pragma unroll
    for (int i = 0; i < 4; i++)
#pragma unroll
        for (int j = 0; j < 4; j++) acc[i][j] = (f32x4){0.f, 0.f, 0.f, 0.f};

    for (int k32 = 0; k32 < 8; k32++) {
        // stage 40 tiles (24 A + 8 Bh + 8 Bl), 10 per wave
#pragma unroll
        for (int i = 0; i < 10; i++) {
            int tau = wave * 10 + i;
            if (tau < 24) {
                int s = tau >> 3, mtg = tau & 7;
                gl_lds16(&Wsp[(size_t)s * 65536 +
                              ((size_t)((by * 8 + mtg) * 8 + k32)) * 512 + l * 8],
                         &As[tau][0]);
            } else if (tau < 32) {
                int nt = tau - 24;
                gl_lds16(&Bht[((size_t)((bx * 8 + nt) * 8 + k32)) * 512 + l * 8],
                         &Bhs[nt][0]);
            } else {
                int nt = tau - 32;
                gl_lds16(&Blt[((size_t)((bx * 8 + nt) * 8 + k32)) * 512 + l * 8],
                         &Bls[nt][0]);
            }
        }
        __syncthreads();

        bf16x8 bh[4], bl[4];
#pragma unroll
        for (int nt = 0; nt < 4; nt++) {
            bh[nt] = *(const bf16x8*)&Bhs[wn * 4 + nt][l * 8];
            bl[nt] = *(const bf16x8*)&Bls[wn * 4 + nt][l * 8];
        }
#pragma unroll
        for (int s = 0; s < 3; s++) {
#pragma unroll
            for (int mt = 0; mt < 4; mt++) {
                bf16x8 afr = *(const bf16x8*)&As[s * 8 + wm * 4 + mt][l * 8];
#pragma unroll
                for (int nt = 0; nt < 4; nt++)
                    acc[mt][nt] = __builtin_amdgcn_mfma_f32_16x16x32_bf16(
                        afr, bh[nt], acc[mt][nt], 0, 0, 0);
                if (s < 2) {
#pragma unroll
                    for (int nt = 0; nt < 4; nt++)
                        acc[mt][nt] = __builtin_amdgcn_mfma_f32_16x16x32_bf16(
                            afr, bl[nt], acc[mt][nt], 0, 0, 0);
                }
            }
        }
        __syncthreads();
    }

    int m0 = by * 128, n0 = bx * 128;
#pragma unroll
    for (int mt = 0; mt < 4; mt++)
#pragma unroll
        for (int i = 0; i < 4; i++) {
            int row = m0 + wm * 64 + mt * 16 + quad * 4 + i;
            float i1 = bnp[1024 + row] / sqrtf(bnp[1024 + 768 + row] + EPSB);
            float b1 = bnp[1024 + 256 + row], m1 = bnp[1024 + 512 + row];
            float i2 = bnp[2048 + row] / sqrtf(bnp[2048 + 768 + row] + EPSB);
            float b2 = bnp[2048 + 256 + row], m2 = bnp[2048 + 512 + row];
            float* yr = &Yt[(size_t)row * N_ + n0 + wn * 64 + lcol];
#pragma unroll
            for (int nt = 0; nt < 4; nt++)
                yr[nt * 16] = ((acc[mt][nt][i] - m1) * i1 + b1 - m2) * i2 + b2;
        }
}

// Single-branch wrappers (p chain).
__global__ __launch_bounds__(256) void gemm_s2(const unsigned short* __restrict__ Wsp,
                                               const unsigned short* __restrict__ ST,
                                               float* __restrict__ Y) {
    int t = blockIdx.z;
    gemm_s_core(Wsp, ST + (size_t)t * CN_, Y + (size_t)t * CN_,
                blockIdx.x, blockIdx.y, threadIdx.x);
}
__global__ __launch_bounds__(256) void gemm_f2(const unsigned short* __restrict__ Wsp,
                                               const unsigned short* __restrict__ BhT,
                                               const unsigned short* __restrict__ BlT,
                                               float* __restrict__ Y,
                                               const float* __restrict__ bnp) {
    int t = blockIdx.z;
    gemm_f_core(Wsp, BhT + (size_t)t * CN_, BlT + (size_t)t * CN_,
                Y + (size_t)t * CN_, bnp, blockIdx.x, blockIdx.y, threadIdx.x);
}

// Three-branch mega-dispatch wrappers. by: br = by>>1, m-half = by&1.
struct GSArgs { const unsigned short* W[3]; const unsigned short* ST; float* F[3]; };
__global__ __launch_bounds__(256) void gemm_s3(GSArgs a) {
    int t = blockIdx.z;
    int br = blockIdx.y >> 1, byl = blockIdx.y & 1;
    gemm_s_core(a.W[br], a.ST + (size_t)t * CN_, a.F[br] + (size_t)t * CN_,
                blockIdx.x, byl, threadIdx.x);
}
struct GFArgs {
    const unsigned short* W[3];
    const unsigned short* Ph[3];
    const unsigned short* Pl[3];
    float* F[3];
    const float* bn[3];
};
__global__ __launch_bounds__(256) void gemm_f3(GFArgs a) {
    int t = blockIdx.z;
    int br = blockIdx.y >> 1, byl = blockIdx.y & 1;
    gemm_f_core(a.W[br], a.Ph[br] + (size_t)t * CN_, a.Pl[br] + (size_t)t * CN_,
                a.F[br] + (size_t)t * CN_, a.bn[br], blockIdx.x, byl, threadIdx.x);
}

// ---------------------------------------------------------------------------
// Bitpacked kv: kv[t,h,d,e] = sum_w popcount(K & V).  Exact integer counts.
__global__ __launch_bounds__(1024) void attn_kv_bp(const u64* __restrict__ Kbp,
                                                   const u64* __restrict__ Vbp,
                                                   float* __restrict__ kvbuf) {
    int th = blockIdx.x;
    int t = th >> 3, h = th & 7;
    const u64* kb = Kbp + ((size_t)t * C_ + h * 32) * 64;
    const u64* vb = Vbp + ((size_t)t * C_ + h * 32) * 64;
    __shared__ u64 ks[32][65];
    __shared__ u64 vs[32][65];
    int tid = threadIdx.x;
    {
        int r = tid >> 5, w2 = (tid & 31) * 2;
        ks[r][w2] = kb[r * 64 + w2];     ks[r][w2 + 1] = kb[r * 64 + w2 + 1];
        vs[r][w2] = vb[r * 64 + w2];     vs[r][w2 + 1] = vb[r * 64 + w2 + 1];
    }
    __syncthreads();
    int d = tid >> 5, e = tid & 31;
    int cnt = 0;
#pragma unroll
    for (int w = 0; w < 64; w++)
        cnt += __popcll(ks[d][w] & vs[e][w]);
    kvbuf[(size_t)th * 1024 + d * 32 + e] = (float)cnt;
}

// ---------------------------------------------------------------------------
// FUSED: o = scale * q.kv  +  LIF(o)  +  fragment layout for the p-GEMM.
__global__ __launch_bounds__(256) void attn_olif(const unsigned char* __restrict__ q,
                                                 const float* __restrict__ kvbuf,
                                                 unsigned short* __restrict__ ST) {
    int h = blockIdx.y;
    int nb = blockIdx.x * 128;
    int tid = threadIdx.x;
    int nj = tid & 127, eh = tid >> 7;
    int n = nb + nj;
    __shared__ float kvs[1024];
    const float scale = 0.17677669529663687f;
    float v[16];
#pragma unroll
    for (int e = 0; e < 16; e++) v[e] = 0.f;
    size_t posbase = ((size_t)((n >> 4) * 8 + h)) * 512 + (size_t)(n & 15) * 8;
    int quad0 = 2 * eh;
#pragma unroll
    for (int t = 0; t < T_; t++) {
        for (int i = tid; i < 1024; i += 256)
            kvs[i] = kvbuf[(size_t)(t * 8 + h) * 1024 + i];
        __syncthreads();
        float acc[16];
#pragma unroll
        for (int e = 0; e < 16; e++) acc[e] = 0.f;
        const unsigned char* qb = q + (size_t)t * CN_ + (size_t)(h * 32) * N_ + n;
#pragma unroll 4
        for (int d = 0; d < 32; d++) {
            float qd = (float)qb[(size_t)d * N_];
#pragma unroll
            for (int e = 0; e < 16; e++)
                acc[e] += qd * kvs[d * 32 + eh * 16 + e];
        }
        bf16x8 w0, w1;
#pragma unroll
        for (int e = 0; e < 16; e++) {
            float o = acc[e] * scale;
            v[e] = v[e] + (o - v[e]) / 2.0f;
            int s = (v[e] - 1.0f >= 0.f) ? 1 : 0;
            short bits = s ? (short)0x3F80 : (short)0;
            if (e < 8) w0[e] = bits; else w1[e - 8] = bits;
            if (s) v[e] = 0.f;
        }
        unsigned short* Stt = ST + (size_t)t * CN_;
        *(bf16x8*)&Stt[posbase + (size_t)(quad0 * 16) * 8] = w0;
        *(bf16x8*)&Stt[posbase + (size_t)((quad0 + 1) * 16) * 8] = w1;
        __syncthreads();
    }
}

// ---------------------------------------------------------------------------
extern "C" void kernel_launch(void* const* d_in, const int* in_sizes, int n_in,
                              void* d_out, int out_size, void* d_ws, size_t ws_size,
                              hipStream_t stream) {
    const float* x = (const float*)d_in[0];
    const float* q_w1 = (const float*)d_in[1];
    const float* q_dw = (const float*)d_in[2];
    const float* q_pw = (const float*)d_in[3];
    const float* q_bn = (const float*)d_in[4];
    const float* k_w1 = (const float*)d_in[5];
    const float* k_dw = (const float*)d_in[6];
    const float* k_pw = (const float*)d_in[7];
    const float* k_bn = (const float*)d_in[8];
    const float* v_w1 = (const float*)d_in[9];
    const float* v_dw = (const float*)d_in[10];
    const float* v_pw = (const float*)d_in[11];
    const float* v_bn = (const float*)d_in[12];
    const float* p_w1 = (const float*)d_in[13];
    const float* p_dw = (const float*)d_in[14];
    const float* p_pw = (const float*)d_in[15];
    const float* p_bn = (const float*)d_in[16];

    const size_t SZ = (size_t)T_ * CN_;   // 8,388,608 elements
    float* out = (float*)d_out;           // p-chain fp32 scratch + final output
    float* F0 = (float*)d_ws;             // branch fp32 buffers (33.5 MB each)
    float* F1 = F0 + SZ;
    float* F2 = F1 + SZ;
    float* P0 = F2 + SZ;                  // bf16 pair buffers (hi|lo in one 33.5MB)
    float* P1 = P0 + SZ;
    float* P2 = P1 + SZ;
    float* bufKV = P2 + SZ;               // 65,536 floats
    unsigned char* xs = (unsigned char*)(bufKV + 65536);   // (unused spare)
    unsigned char* sq = xs + SZ;                           // u8 spikes (q)
    u64* kbp = (u64*)(sq + SZ);
    u64* vbp = kbp + (SZ >> 6);
    unsigned short* wspA = (unsigned short*)(vbp + (SZ >> 6));  // 8*3*65536
    unsigned short* ST = wspA + 8 * 3 * 65536;                  // SZ shorts
    // ws total: ~240.4 MB (<256MiB)

    unsigned short* P0h = (unsigned short*)P0; unsigned short* P0l = P0h + SZ;
    unsigned short* P1h = (unsigned short*)P1; unsigned short* P1l = P1h + SZ;
    unsigned short* P2h = (unsigned short*)P2; unsigned short* P2l = P2h + SZ;

    WPtrs wp;
    wp.w[0] = q_w1; wp.w[1] = q_pw; wp.w[2] = k_w1; wp.w[3] = k_pw;
    wp.w[4] = v_w1; wp.w[5] = v_pw; wp.w[6] = p_w1; wp.w[7] = p_pw;
    split_w<<<dim3(256, 8), dim3(256), 0, stream>>>(wp, wspA);
    const size_t WS3 = 3 * 65536;

    // x -> LIF -> spike fragments (one fused dispatch)
    lif_x_frag<<<dim3(N_ / 32, C_ / 8), dim3(256), 0, stream>>>(x, ST);

    // q,k,v first GEMMs in one dispatch (1536 blocks = 6/CU)
    GSArgs gs;
    gs.W[0] = wspA + 0 * WS3; gs.W[1] = wspA + 2 * WS3; gs.W[2] = wspA + 4 * WS3;
    gs.ST = ST; gs.F[0] = F0; gs.F[1] = F1; gs.F[2] = F2;
    gemm_s3<<<dim3(N_ / 128, 6, T_), dim3(256), 0, stream>>>(gs);

    // q,k,v dw+BN+split in one dispatch
    DArgs da;
    da.F[0] = F0; da.F[1] = F1; da.F[2] = F2;
    da.dw[0] = q_dw; da.dw[1] = k_dw; da.dw[2] = v_dw;
    da.bn[0] = q_bn; da.bn[1] = k_bn; da.bn[2] = v_bn;
    da.Ph[0] = P0h; da.Ph[1] = P1h; da.Ph[2] = P2h;
    da.Pl[0] = P0l; da.Pl[1] = P1l; da.Pl[2] = P2l;
    dw3<<<dim3(16, 32, 3 * T_), dim3(256), 0, stream>>>(da);

    // q,k,v second GEMMs in one dispatch
    GFArgs gf;
    gf.W[0] = wspA + 1 * WS3; gf.W[1] = wspA + 3 * WS3; gf.W[2] = wspA + 5 * WS3;
    gf.Ph[0] = P0h; gf.Ph[1] = P1h; gf.Ph[2] = P2h;
    gf.Pl[0] = P0l; gf.Pl[1] = P1l; gf.Pl[2] = P2l;
    gf.F[0] = F0; gf.F[1] = F1; gf.F[2] = F2;
    gf.bn[0] = q_bn; gf.bn[1] = k_bn; gf.bn[2] = v_bn;
    gemm_f3<<<dim3(N_ / 128, 6, T_), dim3(256), 0, stream>>>(gf);

    // q,k,v LIFs in one dispatch (q -> u8, k/v -> bitpacked)
    LArgs la;
    la.F[0] = F0; la.F[1] = F1; la.F[2] = F2;
    la.sq = sq; la.kbp = kbp; la.vbp = vbp;
    lif3<<<dim3(CN_ / 256, 3), dim3(256), 0, stream>>>(la);

    // attention: exact popcount kv, then fused o+LIF+fragments -> ST
    attn_kv_bp<<<dim3(64), dim3(1024), 0, stream>>>(kbp, vbp, bufKV);
    attn_olif<<<dim3(N_ / 128, 8), dim3(256), 0, stream>>>(sq, bufKV, ST);

    // p branch: gemm1 -> out (fp32), fused dw+split -> P0 pair, gemm2 -> out
    gemm_s2<<<dim3(N_ / 128, C_ / 128, T_), dim3(256), 0, stream>>>(wspA + 6 * WS3, ST, out);
    dw_bn_split<<<dim3(16, 32, T_), dim3(256), 0, stream>>>(out, p_dw, p_bn, P0h, P0l);
    gemm_f2<<<dim3(N_ / 128, C_ / 128, T_), dim3(256), 0, stream>>>(wspA + 7 * WS3, P0h, P0l, out, p_bn);
}